// Round 1
// baseline (171.855 us; speedup 1.0000x reference)
//
#include <hip/hip_runtime.h>
#include <math.h>

typedef unsigned short u16;
typedef unsigned int   u32;
typedef __bf16 bf16x8 __attribute__((ext_vector_type(8)));
typedef float  f32x4  __attribute__((ext_vector_type(4)));
typedef u16    u16x8  __attribute__((ext_vector_type(8)));
typedef u16    u16x4  __attribute__((ext_vector_type(4)));

#define B_TOT 16384
#define DM_   1024
#define H_    256

// ---- workspace layout (bytes) ----
// proj  bf16 [B][5][256] : 0          .. 41,943,040
// scores f32 [B][5]      : 41,943,040 .. 42,270,720
// Wp_mri bf16 [4][256][1024]: 42,270,720 .. 44,367,872
// Wa1 bf16 [64][256]     : 44,367,872 .. 44,400,640
// Wc1 bf16 [128][256]    : 44,400,640 .. 44,466,176
// Wc2 bf16 [64][128]     : 44,466,176 .. 44,482,560
#define WS_SCORES 41943040
#define WS_WP     42270720
#define WS_WA1    44367872
#define WS_WC1    44400640
#define WS_WC2    44466176

__device__ __forceinline__ u16 f2bf(float f){      // RNE f32->bf16
  u32 u = __builtin_bit_cast(u32, f);
  u += 0x7fffu + ((u >> 16) & 1u);
  return (u16)(u >> 16);
}
__device__ __forceinline__ float bf2f(u16 h){
  return __builtin_bit_cast(float, ((u32)h) << 16);
}
__device__ __forceinline__ f32x4 mfma16(bf16x8 a, bf16x8 b, f32x4 c){
  return __builtin_amdgcn_mfma_f32_16x16x32_bf16(a, b, c, 0, 0, 0);
}

// ---------------- K0: weight conversions to bf16 ----------------
__global__ void k0_convert(const float* __restrict__ s0, u16* __restrict__ d0, int n0,
                           const float* __restrict__ s1, u16* __restrict__ d1, int n1,
                           const float* __restrict__ s2, u16* __restrict__ d2, int n2,
                           const float* __restrict__ s3, u16* __restrict__ d3, int n3)
{
  int total4 = (n0 + n1 + n2 + n3) >> 2;
  for (int i = blockIdx.x * blockDim.x + threadIdx.x; i < total4; i += gridDim.x * blockDim.x){
    int e = i << 2;
    const float* s; u16* d; int off;
    if (e < n0)            { s = s0; d = d0; off = e; }
    else if (e < n0+n1)    { s = s1; d = d1; off = e - n0; }
    else if (e < n0+n1+n2) { s = s2; d = d2; off = e - n0 - n1; }
    else                   { s = s3; d = d3; off = e - n0 - n1 - n2; }
    f32x4 f = *(const f32x4*)(s + off);
    u16x4 h = { f2bf(f[0]), f2bf(f[1]), f2bf(f[2]), f2bf(f[3]) };
    *(u16x4*)(d + off) = h;
  }
}

// ---------------- K1: projection GEMM + attention-MLP scores ----------------
// grid (128, 4); block 512 = 8 waves. BM=128, BN=256(all H), BK=64, K=1024.
// LDS: A dbuf 2x16KB @0, W dbuf 2x32KB @32768 (GEMM phase);
//      proj tile bf16 [128][256] @0 (epilogue); clinical staging @98304. Total 110592.
__global__ __launch_bounds__(512) void k1_proj(
    const float* __restrict__ ft1, const float* __restrict__ ft1c,
    const float* __restrict__ ft2, const float* __restrict__ ftfl,
    const float* __restrict__ fcl,
    const u16* __restrict__ Wpbf, const float* __restrict__ bpm,
    const float* __restrict__ Wpcl, const float* __restrict__ bpcl,
    const u16* __restrict__ Wa1bf, const float* __restrict__ ba1,
    const float* __restrict__ Wa2, const float* __restrict__ ba2,
    u16* __restrict__ proj, float* __restrict__ scores)
{
  extern __shared__ char lds[];
  const int m   = blockIdx.y;
  const int b0  = blockIdx.x * 128;
  const int tid = threadIdx.x;
  const int lane = tid & 63;
  const int wv = tid >> 6;            // wave 0..7
  const int wm = wv >> 2, wn = wv & 3; // wave grid 2(M)x4(N), 64x64 tiles
  const int l15 = lane & 15, l4 = lane >> 4;

  const float* Am = (m == 0) ? ft1 : ((m == 1) ? ft1c : ((m == 2) ? ft2 : ftfl));
  const u16*   Wm = Wpbf + (size_t)m * (H_ * DM_);

  const int ar  = tid >> 4;   // A staging row base (0..31), +32*i
  const int ac4 = tid & 15;   // float4 index within BK row

  f32x4 acc[4][4];
  #pragma unroll
  for (int i = 0; i < 4; i++)
    #pragma unroll
    for (int j = 0; j < 4; j++) acc[i][j] = f32x4{0.f, 0.f, 0.f, 0.f};

  // prologue: stage k-tile 0 into buf0
  #pragma unroll
  for (int i = 0; i < 4; i++){
    int r = ar + 32 * i;
    f32x4 a = *(const f32x4*)(Am + (size_t)(b0 + r) * DM_ + ac4 * 4);
    u16x4 h = { f2bf(a[0]), f2bf(a[1]), f2bf(a[2]), f2bf(a[3]) };
    *(u16x4*)(lds + r * 128 + ((ac4 * 8) ^ ((r & 7) << 4))) = h;
  }
  #pragma unroll
  for (int i = 0; i < 4; i++){
    int q = i * 512 + tid; int r = q >> 3, c = q & 7;
    u16x8 w = *(const u16x8*)(Wm + (size_t)r * DM_ + c * 8);
    *(u16x8*)(lds + 32768 + r * 128 + ((c * 16) ^ ((r & 7) << 4))) = w;
  }
  __syncthreads();

  for (int kt = 0; kt < 16; ++kt){
    const int cur = kt & 1;
    f32x4 aR[4]; u16x8 wR[4];
    const bool pf = (kt < 15);
    if (pf){  // issue next-tile global loads early (latency hides under MFMA)
      #pragma unroll
      for (int i = 0; i < 4; i++){
        int r = ar + 32 * i;
        aR[i] = *(const f32x4*)(Am + (size_t)(b0 + r) * DM_ + (kt + 1) * 64 + ac4 * 4);
      }
      #pragma unroll
      for (int i = 0; i < 4; i++){
        int q = i * 512 + tid; int r = q >> 3, c = q & 7;
        wR[i] = *(const u16x8*)(Wm + (size_t)r * DM_ + (kt + 1) * 64 + c * 8);
      }
    }
    char* Ab = lds + cur * 16384;
    char* Wb = lds + 32768 + cur * 32768;
    #pragma unroll
    for (int kk = 0; kk < 2; kk++){
      int kb = kk * 64 + l4 * 16;
      bf16x8 af[4];
      #pragma unroll
      for (int mf = 0; mf < 4; mf++){
        int r = wm * 64 + mf * 16 + l15;
        af[mf] = *(const bf16x8*)(Ab + r * 128 + (kb ^ ((r & 7) << 4)));
      }
      #pragma unroll
      for (int nf = 0; nf < 4; nf++){
        int r = wn * 64 + nf * 16 + l15;
        bf16x8 bfr = *(const bf16x8*)(Wb + r * 128 + (kb ^ ((r & 7) << 4)));
        #pragma unroll
        for (int mf = 0; mf < 4; mf++)
          acc[mf][nf] = mfma16(af[mf], bfr, acc[mf][nf]);
      }
    }
    if (pf){  // convert + write next tile into other buffer
      char* An = lds + (cur ^ 1) * 16384;
      char* Wn = lds + 32768 + (cur ^ 1) * 32768;
      #pragma unroll
      for (int i = 0; i < 4; i++){
        int r = ar + 32 * i;
        u16x4 h = { f2bf(aR[i][0]), f2bf(aR[i][1]), f2bf(aR[i][2]), f2bf(aR[i][3]) };
        *(u16x4*)(An + r * 128 + ((ac4 * 8) ^ ((r & 7) << 4))) = h;
      }
      #pragma unroll
      for (int i = 0; i < 4; i++){
        int q = i * 512 + tid; int r = q >> 3, c = q & 7;
        *(u16x8*)(Wn + r * 128 + ((c * 16) ^ ((r & 7) << 4))) = wR[i];
      }
    }
    __syncthreads();
  }

  // shared epilogue: copy proj tile (in ldsP @0, swizzled) to global; MLP -> scores
  auto epilogue = [&](int mm){
    #pragma unroll
    for (int i = 0; i < 8; i++){
      int q = i * 512 + tid;
      int r = q >> 5, c = q & 31;
      u16x8 v = *(const u16x8*)(lds + r * 512 + ((c * 16) ^ ((r & 7) << 4)));
      *(u16x8*)((char*)proj + ((size_t)(b0 + r) * 1280 + mm * 256) * 2 + c * 16) = v;
    }
    // MLP: wave wv owns rows [wv*16, wv*16+16). t = tanh(P@Wa1^T + ba1); score = t.Wa2 + ba2
    f32x4 a2[4];
    #pragma unroll
    for (int nf = 0; nf < 4; nf++) a2[nf] = f32x4{0.f, 0.f, 0.f, 0.f};
    #pragma unroll
    for (int kk = 0; kk < 8; kk++){
      int kb = kk * 64 + l4 * 16;
      int r = wv * 16 + l15;
      bf16x8 af = *(const bf16x8*)(lds + r * 512 + (kb ^ ((r & 7) << 4)));
      #pragma unroll
      for (int nf = 0; nf < 4; nf++){
        int n = nf * 16 + l15;
        bf16x8 bfr = *(const bf16x8*)((const char*)Wa1bf + n * 512 + kb);
        a2[nf] = mfma16(af, bfr, a2[nf]);
      }
    }
    float p0 = 0.f, p1 = 0.f, p2 = 0.f, p3 = 0.f;
    #pragma unroll
    for (int nf = 0; nf < 4; nf++){
      int n = nf * 16 + l15;
      float w2 = Wa2[n], bn = ba1[n];
      p0 += tanhf(a2[nf][0] + bn) * w2;
      p1 += tanhf(a2[nf][1] + bn) * w2;
      p2 += tanhf(a2[nf][2] + bn) * w2;
      p3 += tanhf(a2[nf][3] + bn) * w2;
    }
    #pragma unroll
    for (int d = 1; d < 16; d <<= 1){
      p0 += __shfl_xor(p0, d); p1 += __shfl_xor(p1, d);
      p2 += __shfl_xor(p2, d); p3 += __shfl_xor(p3, d);
    }
    if (l15 == 0){
      float bav = ba2[0];
      int rb = wv * 16 + l4 * 4;
      scores[(size_t)(b0 + rb + 0) * 5 + mm] = p0 + bav;
      scores[(size_t)(b0 + rb + 1) * 5 + mm] = p1 + bav;
      scores[(size_t)(b0 + rb + 2) * 5 + mm] = p2 + bav;
      scores[(size_t)(b0 + rb + 3) * 5 + mm] = p3 + bav;
    }
  };

  // write acc (+bias) into ldsP bf16 swizzled [128][512B]
  {
    float bias[4];
    #pragma unroll
    for (int nf = 0; nf < 4; nf++) bias[nf] = bpm[m * 256 + wn * 64 + nf * 16 + l15];
    #pragma unroll
    for (int mf = 0; mf < 4; mf++){
      #pragma unroll
      for (int nf = 0; nf < 4; nf++){
        int cc = wn * 64 + nf * 16 + l15;
        #pragma unroll
        for (int rg = 0; rg < 4; rg++){
          int r = wm * 64 + mf * 16 + l4 * 4 + rg;
          float v = acc[mf][nf][rg] + bias[nf];
          *(u16*)(lds + r * 512 + ((cc * 2) ^ ((r & 7) << 4))) = f2bf(v);
        }
      }
    }
  }
  __syncthreads();
  epilogue(m);

  if (m == 0){  // clinical modality (K=8) handled by the m==0 blocks
    __syncthreads();  // wait for epilogue(0) readers of ldsP
    float* ldsF  = (float*)(lds + 98304);   // [128][8]
    float* ldsWc = (float*)(lds + 102400);  // [256][8]
    if (tid < 256){
      int r = tid >> 1, d4 = (tid & 1) * 4;
      *(f32x4*)(ldsF + r * 8 + d4) = *(const f32x4*)(fcl + (size_t)(b0 + r) * 8 + d4);
    }
    {
      int r = tid >> 1, d4 = (tid & 1) * 4;
      *(f32x4*)(ldsWc + r * 8 + d4) = *(const f32x4*)(Wpcl + r * 8 + d4);
    }
    __syncthreads();
    {
      int col = tid & 255;
      f32x4 wa = *(const f32x4*)(ldsWc + col * 8);
      f32x4 wb = *(const f32x4*)(ldsWc + col * 8 + 4);
      float bias = bpcl[col];
      #pragma unroll 4
      for (int e = 0; e < 64; ++e){
        int r = e * 2 + (tid >> 8);
        f32x4 fa = *(const f32x4*)(ldsF + r * 8);
        f32x4 fb = *(const f32x4*)(ldsF + r * 8 + 4);
        float v = bias + fa[0]*wa[0] + fa[1]*wa[1] + fa[2]*wa[2] + fa[3]*wa[3]
                       + fb[0]*wb[0] + fb[1]*wb[1] + fb[2]*wb[2] + fb[3]*wb[3];
        *(u16*)(lds + r * 512 + ((col * 2) ^ ((r & 7) << 4))) = f2bf(v);
      }
    }
    __syncthreads();
    epilogue(4);
  }
}

// ---------------- K2: softmax + fused + classifier ----------------
// grid 256; block 512 = 8 waves; 64 rows/block, 8 rows/wave (one row at a time per wave).
__global__ __launch_bounds__(512) void k2_cls(
    const u16* __restrict__ proj, const float* __restrict__ scores,
    const u16* __restrict__ Wc1bf, const u16* __restrict__ Wc2bf,
    const float* __restrict__ bc1, const float* __restrict__ g1, const float* __restrict__ be1,
    const float* __restrict__ bc2, const float* __restrict__ g2, const float* __restrict__ be2,
    const float* __restrict__ Wc3, const float* __restrict__ bc3,
    float* __restrict__ outp)
{
  extern __shared__ char lds[];
  char* c1w = lds;                       // [128][512B] bf16, chunk-XOR swizzled
  char* c2w = lds + 65536;               // [64][256B]  bf16, chunk-XOR swizzled
  float* fusedL = (float*)(lds + 81920); // [8][256] f32
  float* h1L    = (float*)(lds + 90112); // [8][128] f32
  float* vecs   = (float*)(lds + 94208);
  float* vbc1 = vecs;       float* vg1 = vecs + 128; float* vbe1 = vecs + 256;
  float* vbc2 = vecs + 384; float* vg2 = vecs + 448; float* vbe2 = vecs + 512;
  float* vw3  = vecs + 576;

  const int tid = threadIdx.x, lane = tid & 63, wv = tid >> 6;
  #pragma unroll
  for (int i = 0; i < 8; i++){
    int q = i * 512 + tid; int o = q >> 5, c = q & 31;
    u16x8 v = *(const u16x8*)(Wc1bf + o * 256 + c * 8);
    *(u16x8*)(c1w + o * 512 + ((c * 16) ^ ((o & 31) << 4))) = v;
  }
  #pragma unroll
  for (int i = 0; i < 2; i++){
    int q = i * 512 + tid; int o = q >> 4, c = q & 15;
    u16x8 v = *(const u16x8*)(Wc2bf + o * 128 + c * 8);
    *(u16x8*)(c2w + o * 256 + ((c * 16) ^ ((o & 15) << 4))) = v;
  }
  if (tid < 128){ vbc1[tid] = bc1[tid]; vg1[tid] = g1[tid]; vbe1[tid] = be1[tid]; }
  else if (tid < 192){ int j = tid & 63; vbc2[j] = bc2[j]; vg2[j] = g2[j]; vbe2[j] = be2[j]; vw3[j] = Wc3[j]; }
  __syncthreads();

  const float bcLl = vbc1[lane], bcLh = vbc1[lane + 64];
  const float g1l = vg1[lane], g1h = vg1[lane + 64];
  const float be1l = vbe1[lane], be1h = vbe1[lane + 64];
  const float bc2l = vbc2[lane], g2l = vg2[lane], be2l = vbe2[lane], w3l = vw3[lane];
  const float bc3v = bc3[0];
  float* fl = fusedL + wv * 256;
  float* hl = h1L + wv * 128;
  const int b0 = blockIdx.x * 64;
  const int swz1 = (lane & 31) << 4;
  const int swz2 = (lane & 15) << 4;

  for (int it = 0; it < 8; ++it){
    const int row = b0 + wv * 8 + it;
    const float* sc = scores + (size_t)row * 5;
    float s0 = sc[0], s1 = sc[1], s2 = sc[2], s3 = sc[3], s4 = sc[4];
    float mx = fmaxf(fmaxf(fmaxf(s0, s1), fmaxf(s2, s3)), s4);
    float e0 = expf(s0-mx), e1 = expf(s1-mx), e2 = expf(s2-mx), e3 = expf(s3-mx), e4 = expf(s4-mx);
    float inv = 1.0f / (e0 + e1 + e2 + e3 + e4);
    float w0 = e0*inv, w1 = e1*inv, w2 = e2*inv, w3 = e3*inv, w4 = e4*inv;
    if (lane < 5){
      float wsel = (lane == 0) ? w0 : ((lane == 1) ? w1 : ((lane == 2) ? w2 : ((lane == 3) ? w3 : w4)));
      outp[B_TOT + (size_t)row * 5 + lane] = wsel;
    }
    const u16* pr = proj + (size_t)row * 1280 + lane * 4;
    f32x4 fu;
    {
      u16x4 p0v = *(const u16x4*)(pr);
      u16x4 p1v = *(const u16x4*)(pr + 256);
      u16x4 p2v = *(const u16x4*)(pr + 512);
      u16x4 p3v = *(const u16x4*)(pr + 768);
      u16x4 p4v = *(const u16x4*)(pr + 1024);
      #pragma unroll
      for (int j = 0; j < 4; j++)
        fu[j] = w0*bf2f(p0v[j]) + w1*bf2f(p1v[j]) + w2*bf2f(p2v[j]) + w3*bf2f(p3v[j]) + w4*bf2f(p4v[j]);
    }
    *(f32x4*)(fl + lane * 4) = fu;   // same-wave LDS in-order: no barrier needed

    // layer 1: outputs o=lane and o=lane+64
    float aL = bcLl, aH = bcLh;
    #pragma unroll 4
    for (int ch = 0; ch < 32; ++ch){
      f32x4 fa = *(const f32x4*)(fl + ch * 8);
      f32x4 fb = *(const f32x4*)(fl + ch * 8 + 4);
      u16x8 wl = *(const u16x8*)(c1w + lane * 512 + ((ch * 16) ^ swz1));
      u16x8 wh = *(const u16x8*)(c1w + (lane + 64) * 512 + ((ch * 16) ^ swz1));
      aL += fa[0]*bf2f(wl[0]) + fa[1]*bf2f(wl[1]) + fa[2]*bf2f(wl[2]) + fa[3]*bf2f(wl[3])
          + fb[0]*bf2f(wl[4]) + fb[1]*bf2f(wl[5]) + fb[2]*bf2f(wl[6]) + fb[3]*bf2f(wl[7]);
      aH += fa[0]*bf2f(wh[0]) + fa[1]*bf2f(wh[1]) + fa[2]*bf2f(wh[2]) + fa[3]*bf2f(wh[3])
          + fb[0]*bf2f(wh[4]) + fb[1]*bf2f(wh[5]) + fb[2]*bf2f(wh[6]) + fb[3]*bf2f(wh[7]);
    }
    float s = aL + aH;
    #pragma unroll
    for (int d = 1; d < 64; d <<= 1) s += __shfl_xor(s, d);
    float m1 = s * 0.0078125f;
    float dL = aL - m1, dH = aH - m1;
    float vq = dL * dL + dH * dH;
    #pragma unroll
    for (int d = 1; d < 64; d <<= 1) vq += __shfl_xor(vq, d);
    float is1 = rsqrtf(vq * 0.0078125f + 1e-5f);
    float hLv = fmaxf(dL * is1 * g1l + be1l, 0.f);
    float hHv = fmaxf(dH * is1 * g1h + be1h, 0.f);
    hl[lane] = hLv; hl[lane + 64] = hHv;

    // layer 2: output o=lane
    float a2 = bc2l;
    #pragma unroll 4
    for (int ch = 0; ch < 16; ++ch){
      f32x4 ha = *(const f32x4*)(hl + ch * 8);
      f32x4 hb = *(const f32x4*)(hl + ch * 8 + 4);
      u16x8 wl = *(const u16x8*)(c2w + lane * 256 + ((ch * 16) ^ swz2));
      a2 += ha[0]*bf2f(wl[0]) + ha[1]*bf2f(wl[1]) + ha[2]*bf2f(wl[2]) + ha[3]*bf2f(wl[3])
          + hb[0]*bf2f(wl[4]) + hb[1]*bf2f(wl[5]) + hb[2]*bf2f(wl[6]) + hb[3]*bf2f(wl[7]);
    }
    float s2s = a2;
    #pragma unroll
    for (int d = 1; d < 64; d <<= 1) s2s += __shfl_xor(s2s, d);
    float m2 = s2s * 0.015625f;
    float d2 = a2 - m2;
    float q2 = d2 * d2;
    #pragma unroll
    for (int d = 1; d < 64; d <<= 1) q2 += __shfl_xor(q2, d);
    float is2 = rsqrtf(q2 * 0.015625f + 1e-5f);
    float h2v = fmaxf(d2 * is2 * g2l + be2l, 0.f);
    float po = h2v * w3l;
    #pragma unroll
    for (int d = 1; d < 64; d <<= 1) po += __shfl_xor(po, d);
    if (lane == 0) outp[row] = po + bc3v;
  }
}

extern "C" void kernel_launch(void* const* d_in, const int* in_sizes, int n_in,
                              void* d_out, int out_size, void* d_ws, size_t ws_size,
                              hipStream_t stream)
{
  (void)in_sizes; (void)n_in; (void)out_size; (void)ws_size;
  const float* ft1  = (const float*)d_in[0];
  const float* ft1c = (const float*)d_in[1];
  const float* ft2  = (const float*)d_in[2];
  const float* ftfl = (const float*)d_in[3];
  const float* fcl  = (const float*)d_in[4];
  const float* Wpmri= (const float*)d_in[5];
  const float* bpm  = (const float*)d_in[6];
  const float* Wpcl = (const float*)d_in[7];
  const float* bpcl = (const float*)d_in[8];
  const float* Wa1  = (const float*)d_in[9];
  const float* ba1  = (const float*)d_in[10];
  const float* Wa2  = (const float*)d_in[11];
  const float* ba2  = (const float*)d_in[12];
  const float* Wc1  = (const float*)d_in[13];
  const float* bc1  = (const float*)d_in[14];
  const float* g1   = (const float*)d_in[15];
  const float* be1  = (const float*)d_in[16];
  const float* Wc2  = (const float*)d_in[17];
  const float* bc2  = (const float*)d_in[18];
  const float* g2   = (const float*)d_in[19];
  const float* be2  = (const float*)d_in[20];
  const float* Wc3  = (const float*)d_in[21];
  const float* bc3  = (const float*)d_in[22];
  float* outp = (float*)d_out;
  char* ws = (char*)d_ws;

  u16*   proj   = (u16*)(ws);
  float* scores = (float*)(ws + WS_SCORES);
  u16*   Wpbf   = (u16*)(ws + WS_WP);
  u16*   Wa1bf  = (u16*)(ws + WS_WA1);
  u16*   Wc1bf  = (u16*)(ws + WS_WC1);
  u16*   Wc2bf  = (u16*)(ws + WS_WC2);

  // allow >64KB dynamic LDS (no-op if unnecessary on ROCm)
  (void)hipFuncSetAttribute((const void*)k1_proj, hipFuncAttributeMaxDynamicSharedMemorySize, 110592);
  (void)hipFuncSetAttribute((const void*)k2_cls, hipFuncAttributeMaxDynamicSharedMemorySize, 96768);

  k0_convert<<<dim3(512), dim3(256), 0, stream>>>(
      Wpmri, Wpbf, 4 * H_ * DM_,
      Wa1,  Wa1bf, 64 * H_,
      Wc1,  Wc1bf, 128 * H_,
      Wc2,  Wc2bf, 64 * 128);

  k1_proj<<<dim3(128, 4), dim3(512), 110592, stream>>>(
      ft1, ft1c, ft2, ftfl, fcl, Wpbf, bpm, Wpcl, bpcl,
      Wa1bf, ba1, Wa2, ba2, proj, scores);

  k2_cls<<<dim3(256), dim3(512), 96768, stream>>>(
      proj, scores, Wc1bf, Wc2bf, bc1, g1, be1, bc2, g2, be2, Wc3, bc3, outp);
}

// Round 2
// 123.618 us; speedup vs baseline: 1.3902x; 1.3902x over previous
//
#include <hip/hip_runtime.h>
#include <math.h>

typedef unsigned short u16;
typedef unsigned int   u32;
typedef __bf16 bf16x8 __attribute__((ext_vector_type(8)));
typedef float  f32x4  __attribute__((ext_vector_type(4)));
typedef u16    u16x8  __attribute__((ext_vector_type(8)));
typedef u16    u16x4  __attribute__((ext_vector_type(4)));

#define B_TOT 16384
#define DM_   1024
#define H_    256

// ---- workspace layout (bytes) ----
#define WS_SCORES 41943040   // proj bf16 [B][5][256] : 0 .. 41,943,040
#define WS_WP     42270720   // scores f32 [B][5]
#define WS_WA1    44367872   // Wp_mri bf16 [4][256][1024]
#define WS_WC1    44400640   // Wa1 bf16 [64][256]
#define WS_WC2    44466176   // Wc1 bf16 [128][256]; Wc2 bf16 [64][128] after

__device__ __forceinline__ u16 f2bf(float f){
  __bf16 h = (__bf16)f;                 // RNE, compiler can pack (v_cvt_pk_bf16_f32)
  return __builtin_bit_cast(u16, h);
}
__device__ __forceinline__ float bf2f(u16 h){
  return __builtin_bit_cast(float, ((u32)h) << 16);
}
__device__ __forceinline__ u16x4 cvt4(f32x4 a){
  u16x4 h;
  #pragma unroll
  for (int j = 0; j < 4; j++) h[j] = f2bf(a[j]);
  return h;
}
__device__ __forceinline__ f32x4 mfma16(bf16x8 a, bf16x8 b, f32x4 c){
  return __builtin_amdgcn_mfma_f32_16x16x32_bf16(a, b, c, 0, 0, 0);
}

// ---------------- K0: weight conversions to bf16 ----------------
__global__ void k0_convert(const float* __restrict__ s0, u16* __restrict__ d0, int n0,
                           const float* __restrict__ s1, u16* __restrict__ d1, int n1,
                           const float* __restrict__ s2, u16* __restrict__ d2, int n2,
                           const float* __restrict__ s3, u16* __restrict__ d3, int n3)
{
  int total4 = (n0 + n1 + n2 + n3) >> 2;
  for (int i = blockIdx.x * blockDim.x + threadIdx.x; i < total4; i += gridDim.x * blockDim.x){
    int e = i << 2;
    const float* s; u16* d; int off;
    if (e < n0)            { s = s0; d = d0; off = e; }
    else if (e < n0+n1)    { s = s1; d = d1; off = e - n0; }
    else if (e < n0+n1+n2) { s = s2; d = d2; off = e - n0 - n1; }
    else                   { s = s3; d = d3; off = e - n0 - n1 - n2; }
    f32x4 f = *(const f32x4*)(s + off);
    *(u16x4*)(d + off) = cvt4(f);
  }
}

// ---------------- K1b: clinical projection (K=8) + its attention score ----------------
// 256 blocks x 256 thr (4 waves); 64 rows/block, 16 rows/wave.
__global__ __launch_bounds__(256) void k1b_clin(
    const float* __restrict__ fcl, const float* __restrict__ Wpcl, const float* __restrict__ bpcl,
    const u16* __restrict__ Wa1bf, const float* __restrict__ ba1,
    const float* __restrict__ Wa2, const float* __restrict__ ba2,
    u16* __restrict__ proj, float* __restrict__ scores)
{
  __shared__ u16 pcs[4][16*264];   // per-wave [16 rows][264 u16] (528B stride, 16B aligned, pad)
  const int tid = threadIdx.x, lane = tid & 63, wv = tid >> 6;
  const int l15 = lane & 15, l4 = lane >> 4;
  const int rbase = blockIdx.x * 64 + wv * 16;

  f32x4 wA[4], wB[4];
  f32x4 bp = *(const f32x4*)(bpcl + lane * 4);
  #pragma unroll
  for (int c = 0; c < 4; c++){
    wA[c] = *(const f32x4*)(Wpcl + (lane*4 + c) * 8);
    wB[c] = *(const f32x4*)(Wpcl + (lane*4 + c) * 8 + 4);
  }
  #pragma unroll 4
  for (int r = 0; r < 16; r++){
    int row = rbase + r;
    f32x4 fA = *(const f32x4*)(fcl + (size_t)row * 8);
    f32x4 fB = *(const f32x4*)(fcl + (size_t)row * 8 + 4);
    u16x4 h;
    #pragma unroll
    for (int c = 0; c < 4; c++){
      float v = bp[c] + fA[0]*wA[c][0] + fA[1]*wA[c][1] + fA[2]*wA[c][2] + fA[3]*wA[c][3]
                      + fB[0]*wB[c][0] + fB[1]*wB[c][1] + fB[2]*wB[c][2] + fB[3]*wB[c][3];
      h[c] = f2bf(v);
    }
    *(u16x4*)(proj + (size_t)row * 1280 + 1024 + lane * 4) = h;
    *(u16x4*)(&pcs[wv][r * 264 + lane * 4]) = h;
  }
  // t = pc @ Wa1^T (16x64, K=256) via MFMA; same-wave LDS write->read, in-order
  f32x4 at[4];
  #pragma unroll
  for (int nf = 0; nf < 4; nf++) at[nf] = f32x4{0.f,0.f,0.f,0.f};
  #pragma unroll
  for (int kk = 0; kk < 8; kk++){
    bf16x8 a = *(const bf16x8*)((const char*)&pcs[wv][0] + l15*528 + kk*64 + l4*16);
    #pragma unroll
    for (int nf = 0; nf < 4; nf++){
      bf16x8 b = *(const bf16x8*)((const char*)Wa1bf + (nf*16 + l15)*512 + kk*64 + l4*16);
      at[nf] = mfma16(a, b, at[nf]);
    }
  }
  float po[4] = {0.f,0.f,0.f,0.f};
  #pragma unroll
  for (int nf = 0; nf < 4; nf++){
    int col = nf*16 + l15;
    float bb = ba1[col], w2 = Wa2[col];
    #pragma unroll
    for (int rg = 0; rg < 4; rg++) po[rg] += tanhf(at[nf][rg] + bb) * w2;
  }
  #pragma unroll
  for (int rg = 0; rg < 4; rg++){
    #pragma unroll
    for (int d = 1; d < 16; d <<= 1) po[rg] += __shfl_xor(po[rg], d);
  }
  if (l15 == 0){
    float b2 = ba2[0];
    #pragma unroll
    for (int rg = 0; rg < 4; rg++)
      scores[(size_t)(rbase + l4*4 + rg) * 5 + 4] = po[rg] + b2;
  }
}

// ---------------- K1: MRI projection GEMM + attention-MLP scores ----------------
// 512 blocks (XCD-pair swizzled: each XCD serves one modality -> W stays L2-hot),
// 512 thr = 8 waves (2x4 of 64x64). BM=128, BN=256, BK=64, K=1024.
// LDS 64KB: A [128][128B] @0 (16KB), W [256][128B] @16384 (32KB); epilogue overlays [128][512B] @0.
// Single-buffered + register prefetch (T14): issue loads -> MFMA -> barrier -> write -> barrier.
__global__ __launch_bounds__(512, 4) void k1_proj(
    const float* __restrict__ ft1, const float* __restrict__ ft1c,
    const float* __restrict__ ft2, const float* __restrict__ ftfl,
    const u16* __restrict__ Wpbf, const float* __restrict__ bpm,
    const u16* __restrict__ Wa1bf, const float* __restrict__ ba1,
    const float* __restrict__ Wa2, const float* __restrict__ ba2,
    u16* __restrict__ proj, float* __restrict__ scores)
{
  extern __shared__ char lds[];
  const int l  = blockIdx.x;
  const int mm = (l & 7) >> 1;               // modality <- XCD pair
  const int bx = ((l >> 3) << 1) | (l & 1);  // 0..127, bijective
  const int b0 = bx * 128;
  const int tid = threadIdx.x;
  const int lane = tid & 63;
  const int wv = tid >> 6;
  const int wm = wv >> 2, wn = wv & 3;
  const int l15 = lane & 15, l4 = lane >> 4;

  const float* Am = (mm == 0) ? ft1 : ((mm == 1) ? ft1c : ((mm == 2) ? ft2 : ftfl));
  const u16*   Wm = Wpbf + (size_t)mm * (H_ * DM_);

  const int ar  = tid >> 4;   // A staging row base (0..31), +32*i
  const int ac4 = tid & 15;   // f32x4 chunk within BK row

  f32x4 acc[4][4];
  #pragma unroll
  for (int i = 0; i < 4; i++)
    #pragma unroll
    for (int j = 0; j < 4; j++) acc[i][j] = f32x4{0.f,0.f,0.f,0.f};

  // prologue: stage k-tile 0
  #pragma unroll
  for (int i = 0; i < 4; i++){
    int r = ar + 32*i;
    f32x4 a = *(const f32x4*)(Am + (size_t)(b0 + r) * DM_ + ac4 * 4);
    *(u16x4*)(lds + r*128 + ((ac4*8) ^ ((r & 7) << 4))) = cvt4(a);
  }
  #pragma unroll
  for (int i = 0; i < 4; i++){
    int q = i*512 + tid; int r = q >> 3, c = q & 7;
    u16x8 w = *(const u16x8*)(Wm + (size_t)r * DM_ + c * 8);
    *(u16x8*)(lds + 16384 + r*128 + ((c*16) ^ ((r & 7) << 4))) = w;
  }
  __syncthreads();

  for (int kt = 0; kt < 16; ++kt){
    f32x4 aR[4]; u16x8 wR[4];
    if (kt < 15){   // issue next-tile loads; latency hides under MFMA phase
      #pragma unroll
      for (int i = 0; i < 4; i++){
        int r = ar + 32*i;
        aR[i] = *(const f32x4*)(Am + (size_t)(b0 + r) * DM_ + (kt+1)*64 + ac4*4);
      }
      #pragma unroll
      for (int i = 0; i < 4; i++){
        int q = i*512 + tid; int r = q >> 3, c = q & 7;
        wR[i] = *(const u16x8*)(Wm + (size_t)r * DM_ + (kt+1)*64 + c*8);
      }
    }
    #pragma unroll
    for (int kk = 0; kk < 2; kk++){
      int kb = kk*64 + l4*16;
      bf16x8 af[4];
      #pragma unroll
      for (int mf = 0; mf < 4; mf++){
        int r = wm*64 + mf*16 + l15;
        af[mf] = *(const bf16x8*)(lds + r*128 + (kb ^ ((r & 7) << 4)));
      }
      #pragma unroll
      for (int nf = 0; nf < 4; nf++){
        int r = wn*64 + nf*16 + l15;
        bf16x8 bfr = *(const bf16x8*)(lds + 16384 + r*128 + (kb ^ ((r & 7) << 4)));
        #pragma unroll
        for (int mf = 0; mf < 4; mf++)
          acc[mf][nf] = mfma16(af[mf], bfr, acc[mf][nf]);
      }
    }
    __syncthreads();             // all reads of current tile done
    if (kt < 15){
      #pragma unroll
      for (int i = 0; i < 4; i++){
        int r = ar + 32*i;
        *(u16x4*)(lds + r*128 + ((ac4*8) ^ ((r & 7) << 4))) = cvt4(aR[i]);
      }
      #pragma unroll
      for (int i = 0; i < 4; i++){
        int q = i*512 + tid; int r = q >> 3, c = q & 7;
        *(u16x8*)(lds + 16384 + r*128 + ((c*16) ^ ((r & 7) << 4))) = wR[i];
      }
      __syncthreads();           // writes visible
    }
  }

  // epilogue: acc(+bias) -> lds [128][512B] swizzled
  {
    float bias[4];
    #pragma unroll
    for (int nf = 0; nf < 4; nf++) bias[nf] = bpm[mm*256 + wn*64 + nf*16 + l15];
    #pragma unroll
    for (int mf = 0; mf < 4; mf++){
      #pragma unroll
      for (int nf = 0; nf < 4; nf++){
        int cc = wn*64 + nf*16 + l15;
        #pragma unroll
        for (int rg = 0; rg < 4; rg++){
          int r = wm*64 + mf*16 + l4*4 + rg;
          *(u16*)(lds + r*512 + ((cc*2) ^ ((r & 7) << 4))) = f2bf(acc[mf][nf][rg] + bias[nf]);
        }
      }
    }
  }
  __syncthreads();

  // proj tile -> global
  #pragma unroll
  for (int i = 0; i < 8; i++){
    int q = i*512 + tid;
    int r = q >> 5, c = q & 31;
    u16x8 v = *(const u16x8*)(lds + r*512 + ((c*16) ^ ((r & 7) << 4)));
    *(u16x8*)((char*)proj + (size_t)(b0 + r) * 2560 + mm*512 + c*16) = v;
  }
  // attention MLP: wave wv owns rows [wv*16, wv*16+16)
  {
    f32x4 a2[4];
    #pragma unroll
    for (int nf = 0; nf < 4; nf++) a2[nf] = f32x4{0.f,0.f,0.f,0.f};
    #pragma unroll
    for (int kk = 0; kk < 8; kk++){
      int kb = kk*64 + l4*16;
      int r = wv*16 + l15;
      bf16x8 af = *(const bf16x8*)(lds + r*512 + (kb ^ ((r & 7) << 4)));
      #pragma unroll
      for (int nf = 0; nf < 4; nf++){
        int n = nf*16 + l15;
        bf16x8 bfr = *(const bf16x8*)((const char*)Wa1bf + n*512 + kb);
        a2[nf] = mfma16(af, bfr, a2[nf]);
      }
    }
    float p0 = 0.f, p1 = 0.f, p2 = 0.f, p3 = 0.f;
    #pragma unroll
    for (int nf = 0; nf < 4; nf++){
      int n = nf*16 + l15;
      float w2 = Wa2[n], bn = ba1[n];
      p0 += tanhf(a2[nf][0] + bn) * w2;
      p1 += tanhf(a2[nf][1] + bn) * w2;
      p2 += tanhf(a2[nf][2] + bn) * w2;
      p3 += tanhf(a2[nf][3] + bn) * w2;
    }
    #pragma unroll
    for (int d = 1; d < 16; d <<= 1){
      p0 += __shfl_xor(p0, d); p1 += __shfl_xor(p1, d);
      p2 += __shfl_xor(p2, d); p3 += __shfl_xor(p3, d);
    }
    if (l15 == 0){
      float bav = ba2[0];
      int rb = wv*16 + l4*4;
      scores[(size_t)(b0 + rb + 0)*5 + mm] = p0 + bav;
      scores[(size_t)(b0 + rb + 1)*5 + mm] = p1 + bav;
      scores[(size_t)(b0 + rb + 2)*5 + mm] = p2 + bav;
      scores[(size_t)(b0 + rb + 3)*5 + mm] = p3 + bav;
    }
  }
}

// ---------------- K2: softmax + fuse + MFMA classifier ----------------
// 256 blocks x 256 thr (4 waves); 64 rows/block, 16 rows/wave (one M-tile).
__global__ __launch_bounds__(256) void k2_cls(
    const u16* __restrict__ proj, const float* __restrict__ scores,
    const u16* __restrict__ Wc1bf, const u16* __restrict__ Wc2bf,
    const float* __restrict__ bc1, const float* __restrict__ g1, const float* __restrict__ be1,
    const float* __restrict__ bc2, const float* __restrict__ g2, const float* __restrict__ be2,
    const float* __restrict__ Wc3, const float* __restrict__ bc3,
    float* __restrict__ outp)
{
  __shared__ u16 h1s[4][16*136];   // per-wave h1 transpose bounce, 272B row stride
  const int tid = threadIdx.x, lane = tid & 63, wv = tid >> 6;
  const int l15 = lane & 15, l4 = lane >> 4;
  const int b0 = blockIdx.x * 64;
  const int rowA = b0 + wv*16 + l15;

  // softmax over the 5 modality scores for rowA
  const float* sc = scores + (size_t)rowA * 5;
  float s0 = sc[0], s1 = sc[1], s2 = sc[2], s3 = sc[3], s4 = sc[4];
  float mx = fmaxf(fmaxf(fmaxf(s0, s1), fmaxf(s2, s3)), s4);
  float e0 = expf(s0-mx), e1 = expf(s1-mx), e2 = expf(s2-mx), e3 = expf(s3-mx), e4 = expf(s4-mx);
  float inv = 1.0f / (e0 + e1 + e2 + e3 + e4);
  float w0 = e0*inv, w1 = e1*inv, w2 = e2*inv, w3 = e3*inv, w4 = e4*inv;
  if (l4 == 0){
    float* ap = outp + B_TOT + (size_t)rowA * 5;
    ap[0] = w0; ap[1] = w1; ap[2] = w2; ap[3] = w3; ap[4] = w4;
  }

  // fused row directly in MFMA A-fragment layout (lane: row=l15, k=kk*32+l4*8)
  bf16x8 af[8];
  const u16* pr = proj + (size_t)rowA * 1280 + l4*8;
  #pragma unroll
  for (int kk = 0; kk < 8; kk++){
    u16x8 p0v = *(const u16x8*)(pr + kk*32);
    u16x8 p1v = *(const u16x8*)(pr + 256  + kk*32);
    u16x8 p2v = *(const u16x8*)(pr + 512  + kk*32);
    u16x8 p3v = *(const u16x8*)(pr + 768  + kk*32);
    u16x8 p4v = *(const u16x8*)(pr + 1024 + kk*32);
    bf16x8 a;
    #pragma unroll
    for (int j = 0; j < 8; j++)
      a[j] = (__bf16)(w0*bf2f(p0v[j]) + w1*bf2f(p1v[j]) + w2*bf2f(p2v[j])
                    + w3*bf2f(p3v[j]) + w4*bf2f(p4v[j]));
    af[kk] = a;
  }

  // layer1: [16 x 128] = fused @ Wc1^T, B-frags streamed from L1/L2
  f32x4 acc1[8];
  #pragma unroll
  for (int of = 0; of < 8; of++) acc1[of] = f32x4{0.f,0.f,0.f,0.f};
  #pragma unroll
  for (int kk = 0; kk < 8; kk++){
    #pragma unroll
    for (int of = 0; of < 8; of++){
      bf16x8 b = *(const bf16x8*)((const char*)Wc1bf + (of*16 + l15)*512 + kk*64 + l4*16);
      acc1[of] = mfma16(af[kk], b, acc1[of]);
    }
  }
  // bias + LN1 + ReLU; C layout: col = of*16+l15, row = l4*4+rg
  float sum1[4] = {0.f,0.f,0.f,0.f};
  #pragma unroll
  for (int of = 0; of < 8; of++){
    float bb = bc1[of*16 + l15];
    #pragma unroll
    for (int rg = 0; rg < 4; rg++){ acc1[of][rg] += bb; sum1[rg] += acc1[of][rg]; }
  }
  #pragma unroll
  for (int rg = 0; rg < 4; rg++){
    #pragma unroll
    for (int d = 1; d < 16; d <<= 1) sum1[rg] += __shfl_xor(sum1[rg], d);
  }
  float vs1[4] = {0.f,0.f,0.f,0.f};
  float mean1[4];
  #pragma unroll
  for (int rg = 0; rg < 4; rg++) mean1[rg] = sum1[rg] * 0.0078125f;
  #pragma unroll
  for (int of = 0; of < 8; of++)
    #pragma unroll
    for (int rg = 0; rg < 4; rg++){ float dd = acc1[of][rg] - mean1[rg]; vs1[rg] += dd*dd; }
  #pragma unroll
  for (int rg = 0; rg < 4; rg++){
    #pragma unroll
    for (int d = 1; d < 16; d <<= 1) vs1[rg] += __shfl_xor(vs1[rg], d);
  }
  float is1[4];
  #pragma unroll
  for (int rg = 0; rg < 4; rg++) is1[rg] = rsqrtf(vs1[rg] * 0.0078125f + 1e-5f);
  #pragma unroll
  for (int of = 0; of < 8; of++){
    int col = of*16 + l15;
    float gg = g1[col], bb = be1[col];
    #pragma unroll
    for (int rg = 0; rg < 4; rg++){
      float h = fmaxf((acc1[of][rg] - mean1[rg]) * is1[rg] * gg + bb, 0.f);
      h1s[wv][(l4*4 + rg)*136 + col] = f2bf(h);
    }
  }

  // layer2: [16 x 64] = h1 @ Wc2^T; A from per-wave LDS (same-wave, in-order)
  f32x4 acc2[4];
  #pragma unroll
  for (int of = 0; of < 4; of++) acc2[of] = f32x4{0.f,0.f,0.f,0.f};
  #pragma unroll
  for (int kk = 0; kk < 4; kk++){
    bf16x8 a2 = *(const bf16x8*)((const char*)&h1s[wv][0] + l15*272 + kk*64 + l4*16);
    #pragma unroll
    for (int of = 0; of < 4; of++){
      bf16x8 b = *(const bf16x8*)((const char*)Wc2bf + (of*16 + l15)*256 + kk*64 + l4*16);
      acc2[of] = mfma16(a2, b, acc2[of]);
    }
  }
  // bias + LN2 + ReLU + layer3
  float sum2[4] = {0.f,0.f,0.f,0.f};
  #pragma unroll
  for (int of = 0; of < 4; of++){
    float bb = bc2[of*16 + l15];
    #pragma unroll
    for (int rg = 0; rg < 4; rg++){ acc2[of][rg] += bb; sum2[rg] += acc2[of][rg]; }
  }
  #pragma unroll
  for (int rg = 0; rg < 4; rg++){
    #pragma unroll
    for (int d = 1; d < 16; d <<= 1) sum2[rg] += __shfl_xor(sum2[rg], d);
  }
  float mean2[4], vs2[4] = {0.f,0.f,0.f,0.f};
  #pragma unroll
  for (int rg = 0; rg < 4; rg++) mean2[rg] = sum2[rg] * 0.015625f;
  #pragma unroll
  for (int of = 0; of < 4; of++)
    #pragma unroll
    for (int rg = 0; rg < 4; rg++){ float dd = acc2[of][rg] - mean2[rg]; vs2[rg] += dd*dd; }
  #pragma unroll
  for (int rg = 0; rg < 4; rg++){
    #pragma unroll
    for (int d = 1; d < 16; d <<= 1) vs2[rg] += __shfl_xor(vs2[rg], d);
  }
  float po[4] = {0.f,0.f,0.f,0.f};
  #pragma unroll
  for (int of = 0; of < 4; of++){
    int col = of*16 + l15;
    float gg = g2[col], bb = be2[col], w3c = Wc3[col];
    #pragma unroll
    for (int rg = 0; rg < 4; rg++){
      float is2 = rsqrtf(vs2[rg] * 0.015625f + 1e-5f);
      float h = fmaxf((acc2[of][rg] - mean2[rg]) * is2 * gg + bb, 0.f);
      po[rg] += h * w3c;
    }
  }
  #pragma unroll
  for (int rg = 0; rg < 4; rg++){
    #pragma unroll
    for (int d = 1; d < 16; d <<= 1) po[rg] += __shfl_xor(po[rg], d);
  }
  if (l15 == 0){
    float b3 = bc3[0];
    #pragma unroll
    for (int rg = 0; rg < 4; rg++)
      outp[b0 + wv*16 + l4*4 + rg] = po[rg] + b3;
  }
}

extern "C" void kernel_launch(void* const* d_in, const int* in_sizes, int n_in,
                              void* d_out, int out_size, void* d_ws, size_t ws_size,
                              hipStream_t stream)
{
  (void)in_sizes; (void)n_in; (void)out_size; (void)ws_size;
  const float* ft1  = (const float*)d_in[0];
  const float* ft1c = (const float*)d_in[1];
  const float* ft2  = (const float*)d_in[2];
  const float* ftfl = (const float*)d_in[3];
  const float* fcl  = (const float*)d_in[4];
  const float* Wpmri= (const float*)d_in[5];
  const float* bpm  = (const float*)d_in[6];
  const float* Wpcl = (const float*)d_in[7];
  const float* bpcl = (const float*)d_in[8];
  const float* Wa1  = (const float*)d_in[9];
  const float* ba1  = (const float*)d_in[10];
  const float* Wa2  = (const float*)d_in[11];
  const float* ba2  = (const float*)d_in[12];
  const float* Wc1  = (const float*)d_in[13];
  const float* bc1  = (const float*)d_in[14];
  const float* g1   = (const float*)d_in[15];
  const float* be1  = (const float*)d_in[16];
  const float* Wc2  = (const float*)d_in[17];
  const float* bc2  = (const float*)d_in[18];
  const float* g2   = (const float*)d_in[19];
  const float* be2  = (const float*)d_in[20];
  const float* Wc3  = (const float*)d_in[21];
  const float* bc3  = (const float*)d_in[22];
  float* outp = (float*)d_out;
  char* ws = (char*)d_ws;

  u16*   proj   = (u16*)(ws);
  float* scores = (float*)(ws + WS_SCORES);
  u16*   Wpbf   = (u16*)(ws + WS_WP);
  u16*   Wa1bf  = (u16*)(ws + WS_WA1);
  u16*   Wc1bf  = (u16*)(ws + WS_WC1);
  u16*   Wc2bf  = (u16*)(ws + WS_WC2);

  (void)hipFuncSetAttribute((const void*)k1_proj, hipFuncAttributeMaxDynamicSharedMemorySize, 65536);

  k0_convert<<<dim3(512), dim3(256), 0, stream>>>(
      Wpmri, Wpbf, 4 * H_ * DM_,
      Wa1,  Wa1bf, 64 * H_,
      Wc1,  Wc1bf, 128 * H_,
      Wc2,  Wc2bf, 64 * 128);

  k1b_clin<<<dim3(256), dim3(256), 0, stream>>>(
      fcl, Wpcl, bpcl, Wa1bf, ba1, Wa2, ba2, proj, scores);

  k1_proj<<<dim3(512), dim3(512), 65536, stream>>>(
      ft1, ft1c, ft2, ftfl, Wpbf, bpm, Wa1bf, ba1, Wa2, ba2, proj, scores);

  k2_cls<<<dim3(256), dim3(256), 0, stream>>>(
      proj, scores, Wc1bf, Wc2bf, bc1, g1, be1, bc2, g2, be2, Wc3, bc3, outp);
}